// Round 10
// baseline (128.185 us; speedup 1.0000x reference)
//
#include <hip/hip_runtime.h>
#include <stdint.h>

#define HW 4194304      // 2048*2048
#define WIDTH 2048
#define NBLK 2048
#define F(x) ((float)(x))   // double literal -> f32, exactly like numpy scalar promotion

// ---------------------------------------------------------------------------
// Bit-exact replication of glibc sysdeps/ieee754/flt-32/s_cbrtf.c (pre-2.41)
// — what np.cbrt(float32) resolves to on the host. EMPIRICAL RULE: ALL THREE
// channels (fx, fy, fz) must use this exact path, AND the three callsites
// must stay together in ONE function (R9: splitting fy from fx/fz across
// phases failed at exactly 2.73e-2 despite source-identical op sequences).
// Bit-exact micro-opts (validated R5-R8): branchless f64 factor select +
// exact pow2 multiply instead of ldexpf (domain xe in [-6,1]).
// ---------------------------------------------------------------------------
__device__ __forceinline__ float cbrtf_glibc(float x) {
    unsigned int bits = __float_as_uint(x);
    int xe = (int)((bits >> 23) & 0xFF) - 126;
    float xm = __uint_as_float((bits & 0x007FFFFFu) | 0x3F000000u);

    double xmd = (double)xm;
    double p = __dsub_rn(0.697570460207922770, __dmul_rn(0.191502161678719066, xmd));
    p = __dadd_rn(0.492659620528969547, __dmul_rn(p, xmd));
    float u = (float)p;

    float t2 = __fmul_rn(__fmul_rn(u, u), u);   // float, two roundings (as glibc)

    double ud  = (double)u;
    double t2d = (double)t2;
    double num = __dmul_rn(ud, __dadd_rn(t2d, __dmul_rn(2.0, xmd)));
    double den = __dadd_rn(__dmul_rn(2.0, t2d), xmd);

    int idx = 2 + (xe % 3);                     // C trunc semantics, as glibc
    double f = (idx == 2) ? 1.0
             : (idx == 0) ? (1.0 / 1.5874010519681994748)
             : (idx == 1) ? (1.0 / 1.2599210498948731648)
             : (idx == 3) ? 1.2599210498948731648
             :              1.5874010519681994748;
    double ym  = __dmul_rn(__ddiv_rn(num, den), f);
    float ymf = (float)ym;

    int q = xe / 3;                             // in {-2,-1,0} for our domain
    float s = (q == 0) ? 1.0f : ((q == -1) ? 0.5f : 0.25f);
    return __fmul_rn(ymf, s);
}

// Exact forward path — the ONLY forward path (see empirical rule above).
__device__ __forceinline__ void rgb2lab_px(float r, float g, float b,
                                           int& l8, float& A_, float& B_) {
    float X = __fadd_rn(__fadd_rn(__fmul_rn(r, F(0.412453)), __fmul_rn(g, F(0.357580))), __fmul_rn(b, F(0.180423)));
    float Y = __fadd_rn(__fadd_rn(__fmul_rn(r, F(0.212671)), __fmul_rn(g, F(0.715160))), __fmul_rn(b, F(0.072169)));
    float Z = __fadd_rn(__fadd_rn(__fmul_rn(r, F(0.019334)), __fmul_rn(g, F(0.119193))), __fmul_rn(b, F(0.950227)));
    X = __fdiv_rn(X, F(0.950456));
    Z = __fdiv_rn(Z, F(1.088754));
    const float EPS = F(0.008856);
    const float C0  = F(16.0 / 116.0);
    float fx = (X > EPS) ? cbrtf_glibc(X) : __fadd_rn(__fmul_rn(F(7.787), X), C0);
    float fy = (Y > EPS) ? cbrtf_glibc(Y) : __fadd_rn(__fmul_rn(F(7.787), Y), C0);
    float fz = (Z > EPS) ? cbrtf_glibc(Z) : __fadd_rn(__fmul_rn(F(7.787), Z), C0);
    float L  = __fsub_rn(__fmul_rn(F(116.0), fy), F(16.0));
    A_ = __fmul_rn(F(500.0), __fsub_rn(fx, fy));
    B_ = __fmul_rn(F(200.0), __fsub_rn(fy, fz));
    float Lr = rintf(__fmul_rn(L, F(255.0 / 100.0)));
    Lr = fminf(fmaxf(Lr, 0.0f), 255.0f);
    l8 = (int)Lr;
}

// lab2rgb epilogue (value-returning).
__device__ __forceinline__ void lab2rgb_px(float Leq, float A_, float B_,
                                           float& rr, float& gg, float& bb) {
    const float EPS = F(0.008856);
    const float C0  = F(16.0 / 116.0);
    float fy2 = __fdiv_rn(__fadd_rn(Leq, 16.0f), 116.0f);
    float fx2 = __fadd_rn(fy2, __fdiv_rn(A_, 500.0f));
    float fz2 = __fsub_rn(fy2, __fdiv_rn(B_, 200.0f));
    float t3;
    t3 = fx2 * fx2 * fx2;
    float X = ((t3 > EPS) ? t3 : __fdiv_rn(__fsub_rn(fx2, C0), F(7.787))) * F(0.950456);
    t3 = fy2 * fy2 * fy2;
    float Y = ((t3 > EPS) ? t3 : __fdiv_rn(__fsub_rn(fy2, C0), F(7.787))) * F(1.0);
    t3 = fz2 * fz2 * fz2;
    float Z = ((t3 > EPS) ? t3 : __fdiv_rn(__fsub_rn(fz2, C0), F(7.787))) * F(1.088754);
    rr = __fadd_rn(__fadd_rn(__fmul_rn(X, F(3.240479)),  __fmul_rn(Y, F(-1.537150))), __fmul_rn(Z, F(-0.498535)));
    gg = __fadd_rn(__fadd_rn(__fmul_rn(X, F(-0.969256)), __fmul_rn(Y, F(1.875992))),  __fmul_rn(Z, F(0.041556)));
    bb = __fadd_rn(__fadd_rn(__fmul_rn(X, F(0.055648)),  __fmul_rn(Y, F(-0.204043))), __fmul_rn(Z, F(1.057311)));
    rr = fminf(fmaxf(rr, 0.0f), 1.0f);
    gg = fminf(fmaxf(gg, 0.0f), 1.0f);
    bb = fminf(fmaxf(bb, 0.0f), 1.0f);
}

// ---------------------------------------------------------------------------
// LUT build for tile-rows (y0,y1) into lutS[4096] — R2..R8-verified BIT-EXACT
// wave-scan (partial sums are multiples of 2^-8 bounded by 2^16 => exact in
// f32 in any association => identical to reference serial cumsum).
// ---------------------------------------------------------------------------
template<bool ATOMIC_LOADS>
__device__ __forceinline__ void build_luts(const unsigned int* __restrict__ hist,
                                           float* lutS, int y0, int y1, int t) {
    const int lane = t & 63;
    const int w = t >> 6;
    #pragma unroll
    for (int i = 0; i < 4; ++i) {
        int gidx = w * 4 + i;             // 0..15
        int trow = gidx >> 3;             // 0 = y0 row, 1 = y1 row
        int tcol = gidx & 7;
        int tile = (trow ? y1 : y0) * 8 + tcol;
        float h0, h1, h2, h3;
        if (ATOMIC_LOADS) {
            const unsigned int* hp = hist + tile * 256 + lane * 4;
            h0 = (float)__hip_atomic_load(&hp[0], __ATOMIC_RELAXED, __HIP_MEMORY_SCOPE_AGENT);
            h1 = (float)__hip_atomic_load(&hp[1], __ATOMIC_RELAXED, __HIP_MEMORY_SCOPE_AGENT);
            h2 = (float)__hip_atomic_load(&hp[2], __ATOMIC_RELAXED, __HIP_MEMORY_SCOPE_AGENT);
            h3 = (float)__hip_atomic_load(&hp[3], __ATOMIC_RELAXED, __HIP_MEMORY_SCOPE_AGENT);
        } else {
            uint4 hv = *(const uint4*)(hist + tile * 256 + lane * 4);
            h0 = (float)hv.x; h1 = (float)hv.y; h2 = (float)hv.z; h3 = (float)hv.w;
        }
        float e = __fadd_rn(__fadd_rn(fmaxf(h0 - 2560.0f, 0.0f),
                                      fmaxf(h1 - 2560.0f, 0.0f)),
                            __fadd_rn(fmaxf(h2 - 2560.0f, 0.0f),
                                      fmaxf(h3 - 2560.0f, 0.0f)));
        #pragma unroll
        for (int d = 1; d < 64; d <<= 1) e = __fadd_rn(e, __shfl_xor(e, d));
        float ex = __fmul_rn(e, F(1.0 / 256.0));   // pow2 scale, exact
        float v0 = __fadd_rn(fminf(h0, 2560.0f), ex);
        float v1 = __fadd_rn(fminf(h1, 2560.0f), ex);
        float v2 = __fadd_rn(fminf(h2, 2560.0f), ex);
        float v3 = __fadd_rn(fminf(h3, 2560.0f), ex);
        float s0 = v0;
        float s1 = __fadd_rn(s0, v1);
        float s2 = __fadd_rn(s1, v2);
        float s3 = __fadd_rn(s2, v3);
        float sc = s3;
        #pragma unroll
        for (int d = 1; d < 64; d <<= 1) {
            float u2 = __shfl_up(sc, d);
            if (lane >= d) sc = __fadd_rn(sc, u2);
        }
        float excl = __fsub_rn(sc, s3);   // exact: multiples of 2^-8, <= 2^16
        int lb = trow * 2048 + tcol * 256 + lane * 4;
        float c0 = rintf(__fmul_rn(__fadd_rn(excl, s0), F(255.0 / 65536.0)));
        float c1 = rintf(__fmul_rn(__fadd_rn(excl, s1), F(255.0 / 65536.0)));
        float c2 = rintf(__fmul_rn(__fadd_rn(excl, s2), F(255.0 / 65536.0)));
        float c3 = rintf(__fmul_rn(__fadd_rn(excl, s3), F(255.0 / 65536.0)));
        lutS[lb + 0] = fminf(fmaxf(c0, 0.0f), 255.0f);
        lutS[lb + 1] = fminf(fmaxf(c1, 0.0f), 255.0f);
        lutS[lb + 2] = fminf(fmaxf(c2, 0.0f), 255.0f);
        lutS[lb + 3] = fminf(fmaxf(c3, 0.0f), 255.0f);
    }
}

// Bilinear interp + lab2rgb + float4 store for 4 px.
__device__ __forceinline__ void apply4(const float* lutS, int col0, int idx,
        int l80, int l81, int l82, int l83,
        float A0, float A1, float A2, float A3,
        float B0, float B1, float B2, float B3,
        float wy, float omwy, float* __restrict__ out) {
    float4 o_r, o_g, o_b;
#define PIX(J, L8V, AV, BV, OR_, OG_, OB_) {                                      \
    int col = col0 + (J);                                                         \
    float fxc = fminf(fmaxf(((float)col + 0.5f) * (1.0f / 256.0f) - 0.5f, 0.0f), 7.0f); \
    int xi0 = (int)floorf(fxc);                                                   \
    int xi1 = min(xi0 + 1, 7);                                                    \
    float wx = __fsub_rn(fxc, (float)xi0);                                        \
    float omwx = __fsub_rn(1.0f, wx);                                             \
    float g00 = lutS[xi0 * 256 + (L8V)];                                          \
    float g01 = lutS[xi1 * 256 + (L8V)];                                          \
    float g10 = lutS[2048 + xi0 * 256 + (L8V)];                                   \
    float g11 = lutS[2048 + xi1 * 256 + (L8V)];                                   \
    float top_ = __fadd_rn(__fmul_rn(omwx, g00), __fmul_rn(wx, g01));             \
    float bot_ = __fadd_rn(__fmul_rn(omwx, g10), __fmul_rn(wx, g11));             \
    float Leq = __fmul_rn(__fadd_rn(__fmul_rn(omwy, top_), __fmul_rn(wy, bot_)),  \
                          F(100.0 / 255.0));                                      \
    lab2rgb_px(Leq, (AV), (BV), (OR_), (OG_), (OB_));                             \
}
    PIX(0, l80, A0, B0, o_r.x, o_g.x, o_b.x);
    PIX(1, l81, A1, B1, o_r.y, o_g.y, o_b.y);
    PIX(2, l82, A2, B2, o_r.z, o_g.z, o_b.z);
    PIX(3, l83, A3, B3, o_r.w, o_g.w, o_b.w);
#undef PIX
    *(float4*)(out + idx)          = o_r;
    *(float4*)(out + idx + HW)     = o_g;
    *(float4*)(out + idx + 2 * HW) = o_b;
}

// Phase-1 helper for one 4-px chunk: loads, rgb2lab, LDS atomics.
__device__ __forceinline__ void chunk_lab(const float* __restrict__ x,
        unsigned int* h, int rowbase, int col0,
        float& A0, float& A1, float& A2, float& A3,
        float& B0, float& B1, float& B2, float& B3, unsigned& pk) {
    const int idx = rowbase + col0;
    float4 r4 = *(const float4*)(x + idx);
    float4 g4 = *(const float4*)(x + idx + HW);
    float4 b4 = *(const float4*)(x + idx + 2 * HW);
    int l0, l1, l2, l3;
    rgb2lab_px(r4.x, g4.x, b4.x, l0, A0, B0);
    rgb2lab_px(r4.y, g4.y, b4.y, l1, A1, B1);
    rgb2lab_px(r4.z, g4.z, b4.z, l2, A2, B2);
    rgb2lab_px(r4.w, g4.w, b4.w, l3, A3, B3);
    const int hb = (col0 >> 8) << 8;   // tile uniform over the 4 px
    atomicAdd(&h[hb + l0], 1u);
    atomicAdd(&h[hb + l1], 1u);
    atomicAdd(&h[hb + l2], 1u);
    atomicAdd(&h[hb + l3], 1u);
    pk = (unsigned)l0 | ((unsigned)l1 << 8) | ((unsigned)l2 << 16) | ((unsigned)l3 << 24);
}

// Global hist merge with y-rotated sweep order (R8-verified; commutative
// integer atomics — bit-identical result).
__device__ __forceinline__ void merge_hist(unsigned int* __restrict__ hist,
                                           const unsigned int* h, int y, int t) {
    unsigned int* gh = hist + (y >> 8) * 2048;
    #pragma unroll
    for (int ii = 0; ii < 8; ++ii) {
        int i = (ii + (y & 7)) & 7;
        unsigned int v = h[i * 256 + t];
        if (v) atomicAdd(&gh[i * 256 + t], v);
    }
}

// Signal own tile-row done; bounded wait for the two needed tile-rows.
// R5-R8-verified device-scope pattern.
__device__ __forceinline__ void signal_and_wait(unsigned int* rowdone,
                                                int myrow, int y0, int y1, int t) {
    if (t == 0) {
        __threadfence();                                   // release hist atomics
        atomicAdd(&rowdone[myrow], 1u);                    // device-scope
        long limit = 1L << 18;                             // bounded
        while (limit-- > 0) {
            unsigned a = __hip_atomic_load(&rowdone[y0], __ATOMIC_ACQUIRE, __HIP_MEMORY_SCOPE_AGENT);
            unsigned b = __hip_atomic_load(&rowdone[y1], __ATOMIC_ACQUIRE, __HIP_MEMORY_SCOPE_AGENT);
            if (a == 256u && b == 256u) break;
            __builtin_amdgcn_s_sleep(2);
        }
    }
    __syncthreads();
}

// ===========================================================================
// Mode 0: FULL register state (16 f32 + 2 u32 across the wait). Gated on
// occupancy (2048 co-resident) AND localSizeBytes==0 (no spill).
// ===========================================================================
__global__ __launch_bounds__(256, 8) void k_fused_reg(const float* __restrict__ x,
        unsigned int* __restrict__ hist, unsigned int* __restrict__ rowdone,
        float* __restrict__ out) {
    __shared__ float lutS[4096];   // first 8 KB doubles as u32 hist in phase 1
    unsigned int* h = (unsigned int*)lutS;
    const int t = threadIdx.x;
    const int y = blockIdx.x;

    #pragma unroll
    for (int i = 0; i < 8; ++i) h[i * 256 + t] = 0;
    __syncthreads();

    const int rowbase = y * WIDTH;
    float A0, A1, A2, A3, A4, A5, A6, A7;
    float B0, B1, B2, B3, B4, B5, B6, B7;
    unsigned pk0, pk1;
    chunk_lab(x, h, rowbase, 4 * t,        A0, A1, A2, A3, B0, B1, B2, B3, pk0);
    __builtin_amdgcn_sched_barrier(0);
    chunk_lab(x, h, rowbase, 1024 + 4 * t, A4, A5, A6, A7, B4, B5, B6, B7, pk1);
    __builtin_amdgcn_sched_barrier(0);
    __syncthreads();
    merge_hist(hist, h, y, t);
    __syncthreads();

    float fyc = fminf(fmaxf(((float)y + 0.5f) * (1.0f / 256.0f) - 0.5f, 0.0f), 7.0f);
    int y0 = (int)floorf(fyc);
    int y1 = min(y0 + 1, 7);
    float wy = __fsub_rn(fyc, (float)y0);
    float omwy = __fsub_rn(1.0f, wy);

    signal_and_wait(rowdone, y >> 8, y0, y1, t);

    build_luts<true>(hist, lutS, y0, y1, t);
    __syncthreads();

    apply4(lutS, 4 * t, rowbase + 4 * t,
           (int)(pk0 & 0xFFu), (int)((pk0 >> 8) & 0xFFu),
           (int)((pk0 >> 16) & 0xFFu), (int)((pk0 >> 24) & 0xFFu),
           A0, A1, A2, A3, B0, B1, B2, B3, wy, omwy, out);
    apply4(lutS, 1024 + 4 * t, rowbase + 1024 + 4 * t,
           (int)(pk1 & 0xFFu), (int)((pk1 >> 8) & 0xFFu),
           (int)((pk1 >> 16) & 0xFFu), (int)((pk1 >> 24) & 0xFFu),
           A4, A5, A6, A7, B4, B5, B6, B7, wy, omwy, out);
}

// ===========================================================================
// Mode 1: HALF register state (chunk 0 in regs; chunk 1 via ws). R8-verified
// at 127.47 µs, VGPR 32.
// ===========================================================================
__global__ __launch_bounds__(256, 8) void k_fused_half(const float* __restrict__ x,
        unsigned int* __restrict__ hist, unsigned int* __restrict__ rowdone,
        float* __restrict__ Abuf, float* __restrict__ Bbuf,
        unsigned int* __restrict__ l8buf, float* __restrict__ out) {
    __shared__ float lutS[4096];
    unsigned int* h = (unsigned int*)lutS;
    const int t = threadIdx.x;
    const int y = blockIdx.x;

    #pragma unroll
    for (int i = 0; i < 8; ++i) h[i * 256 + t] = 0;
    __syncthreads();

    const int rowbase = y * WIDTH;
    float A0, A1, A2, A3, B0, B1, B2, B3;
    unsigned pk0;
    chunk_lab(x, h, rowbase, 4 * t, A0, A1, A2, A3, B0, B1, B2, B3, pk0);
    __builtin_amdgcn_sched_barrier(0);
    {
        float Aa, Ab, Ac, Ad, Ba, Bb, Bc, Bd;
        unsigned pk1;
        const int col0 = 1024 + 4 * t;
        const int idx  = rowbase + col0;
        chunk_lab(x, h, rowbase, col0, Aa, Ab, Ac, Ad, Ba, Bb, Bc, Bd, pk1);
        *(float4*)(Abuf + idx) = make_float4(Aa, Ab, Ac, Ad);
        *(float4*)(Bbuf + idx) = make_float4(Ba, Bb, Bc, Bd);
        l8buf[idx >> 2] = pk1;
    }
    __builtin_amdgcn_sched_barrier(0);
    __syncthreads();
    merge_hist(hist, h, y, t);
    __syncthreads();

    float fyc = fminf(fmaxf(((float)y + 0.5f) * (1.0f / 256.0f) - 0.5f, 0.0f), 7.0f);
    int y0 = (int)floorf(fyc);
    int y1 = min(y0 + 1, 7);
    float wy = __fsub_rn(fyc, (float)y0);
    float omwy = __fsub_rn(1.0f, wy);

    signal_and_wait(rowdone, y >> 8, y0, y1, t);

    build_luts<true>(hist, lutS, y0, y1, t);
    __syncthreads();

    apply4(lutS, 4 * t, rowbase + 4 * t,
           (int)(pk0 & 0xFFu), (int)((pk0 >> 8) & 0xFFu),
           (int)((pk0 >> 16) & 0xFFu), (int)((pk0 >> 24) & 0xFFu),
           A0, A1, A2, A3, B0, B1, B2, B3, wy, omwy, out);
    {
        const int col0 = 1024 + 4 * t;
        const int idx  = rowbase + col0;
        float4 a4 = *(const float4*)(Abuf + idx);
        float4 b4 = *(const float4*)(Bbuf + idx);
        unsigned p = l8buf[idx >> 2];
        apply4(lutS, col0, idx,
               (int)(p & 0xFFu), (int)((p >> 8) & 0xFFu),
               (int)((p >> 16) & 0xFFu), (int)((p >> 24) & 0xFFu),
               a4.x, a4.y, a4.z, a4.w, b4.x, b4.y, b4.z, b4.w,
               wy, omwy, out);
    }
}

// ===========================================================================
// Mode 2: fused ws-roundtrip (R5-verified safety net).
// ===========================================================================
__global__ __launch_bounds__(256, 8) void k_fused_ws(const float* __restrict__ x,
        unsigned int* __restrict__ hist, unsigned int* __restrict__ rowdone,
        float* __restrict__ Abuf, float* __restrict__ Bbuf,
        unsigned int* __restrict__ l8buf, float* __restrict__ out) {
    __shared__ float lutS[4096];
    unsigned int* h = (unsigned int*)lutS;
    const int t = threadIdx.x;
    const int y = blockIdx.x;

    #pragma unroll
    for (int i = 0; i < 8; ++i) h[i * 256 + t] = 0;
    __syncthreads();

    const int rowbase = y * WIDTH;
    #pragma unroll
    for (int ch = 0; ch < 2; ++ch) {
        const int col0 = ch * 1024 + 4 * t;
        const int idx  = rowbase + col0;
        float A0, A1, A2, A3, B0, B1, B2, B3;
        unsigned pk;
        chunk_lab(x, h, rowbase, col0, A0, A1, A2, A3, B0, B1, B2, B3, pk);
        *(float4*)(Abuf + idx) = make_float4(A0, A1, A2, A3);
        *(float4*)(Bbuf + idx) = make_float4(B0, B1, B2, B3);
        l8buf[idx >> 2] = pk;
    }
    __syncthreads();
    merge_hist(hist, h, y, t);
    __syncthreads();

    float fyc = fminf(fmaxf(((float)y + 0.5f) * (1.0f / 256.0f) - 0.5f, 0.0f), 7.0f);
    int y0 = (int)floorf(fyc);
    int y1 = min(y0 + 1, 7);
    float wy = __fsub_rn(fyc, (float)y0);
    float omwy = __fsub_rn(1.0f, wy);

    signal_and_wait(rowdone, y >> 8, y0, y1, t);

    build_luts<true>(hist, lutS, y0, y1, t);
    __syncthreads();

    #pragma unroll
    for (int ch = 0; ch < 2; ++ch) {
        const int col0 = ch * 1024 + 4 * t;
        const int idx  = rowbase + col0;
        float4 a4 = *(const float4*)(Abuf + idx);
        float4 b4 = *(const float4*)(Bbuf + idx);
        unsigned p = l8buf[idx >> 2];
        apply4(lutS, col0, idx,
               (int)(p & 0xFFu), (int)((p >> 8) & 0xFFu),
               (int)((p >> 16) & 0xFFu), (int)((p >> 24) & 0xFFu),
               a4.x, a4.y, a4.z, a4.w, b4.x, b4.y, b4.z, b4.w,
               wy, omwy, out);
    }
}

// ===========================================================================
// Mode 3: two-kernel fallback (R4-verified).
// ===========================================================================
__global__ __launch_bounds__(256, 8) void k_hist_ab(const float* __restrict__ x,
        unsigned int* __restrict__ hist,
        float* __restrict__ Abuf, float* __restrict__ Bbuf,
        unsigned int* __restrict__ l8buf, int store) {
    __shared__ unsigned int h[2048];
    const int t = threadIdx.x;
    const int y = blockIdx.x;
    #pragma unroll
    for (int i = 0; i < 8; ++i) h[i * 256 + t] = 0;
    __syncthreads();

    const int rowbase = y * WIDTH;
    #pragma unroll
    for (int ch = 0; ch < 2; ++ch) {
        const int col0 = ch * 1024 + 4 * t;
        const int idx  = rowbase + col0;
        float A0, A1, A2, A3, B0, B1, B2, B3;
        unsigned pk;
        chunk_lab(x, h, rowbase, col0, A0, A1, A2, A3, B0, B1, B2, B3, pk);
        if (store) {
            *(float4*)(Abuf + idx) = make_float4(A0, A1, A2, A3);
            *(float4*)(Bbuf + idx) = make_float4(B0, B1, B2, B3);
            l8buf[idx >> 2] = pk;
        }
    }
    __syncthreads();
    merge_hist(hist, h, y, t);
}

__global__ __launch_bounds__(256, 8) void k_lut_apply(const float* __restrict__ x,
        const unsigned int* __restrict__ hist,
        const float* __restrict__ Abuf, const float* __restrict__ Bbuf,
        const unsigned int* __restrict__ l8buf,
        float* __restrict__ out, int stored) {
    __shared__ float lutS[4096];
    const int t = threadIdx.x;
    const int y = blockIdx.x;

    float fyc = fminf(fmaxf(((float)y + 0.5f) * (1.0f / 256.0f) - 0.5f, 0.0f), 7.0f);
    int y0 = (int)floorf(fyc);
    int y1 = min(y0 + 1, 7);
    float wy = __fsub_rn(fyc, (float)y0);
    float omwy = __fsub_rn(1.0f, wy);

    build_luts<false>(hist, lutS, y0, y1, t);
    __syncthreads();

    const int rowbase = y * WIDTH;
    #pragma unroll
    for (int ch = 0; ch < 2; ++ch) {
        const int col0 = ch * 1024 + 4 * t;
        const int idx  = rowbase + col0;
        float A0, A1, A2, A3, B0, B1, B2, B3;
        int l80, l81, l82, l83;
        if (stored) {
            float4 a4 = *(const float4*)(Abuf + idx);
            float4 b4 = *(const float4*)(Bbuf + idx);
            unsigned p = l8buf[idx >> 2];
            A0 = a4.x; A1 = a4.y; A2 = a4.z; A3 = a4.w;
            B0 = b4.x; B1 = b4.y; B2 = b4.z; B3 = b4.w;
            l80 = (int)(p & 0xFFu); l81 = (int)((p >> 8) & 0xFFu);
            l82 = (int)((p >> 16) & 0xFFu); l83 = (int)((p >> 24) & 0xFFu);
        } else {
            float4 r4 = *(const float4*)(x + idx);
            float4 g4 = *(const float4*)(x + idx + HW);
            float4 b4 = *(const float4*)(x + idx + 2 * HW);
            rgb2lab_px(r4.x, g4.x, b4.x, l80, A0, B0);
            rgb2lab_px(r4.y, g4.y, b4.y, l81, A1, B1);
            rgb2lab_px(r4.z, g4.z, b4.z, l82, A2, B2);
            rgb2lab_px(r4.w, g4.w, b4.w, l83, A3, B3);
        }
        apply4(lutS, col0, idx, l80, l81, l82, l83,
               A0, A1, A2, A3, B0, B1, B2, B3, wy, omwy, out);
    }
}

extern "C" void kernel_launch(void* const* d_in, const int* in_sizes, int n_in,
                              void* d_out, int out_size, void* d_ws, size_t ws_size,
                              hipStream_t stream) {
    const float* x = (const float*)d_in[0];
    float* out = (float*)d_out;
    char* ws = (char*)d_ws;
    unsigned int* hist = (unsigned int*)ws;                 // 64 KiB
    unsigned int* rowdone = (unsigned int*)(ws + 65536);    // 8 x u32
    const size_t off = 131072;
    float* Abuf = (float*)(ws + off);                       // 16 MiB
    float* Bbuf = (float*)(ws + off + (size_t)HW * 4);      // 16 MiB
    unsigned int* l8buf = (unsigned int*)(ws + off + (size_t)HW * 8); // 4 MiB
    const size_t need = off + (size_t)HW * 9;
    const int store = (ws_size >= need) ? 1 : 0;

    // mode: 0=full-reg fused, 1=half-reg fused, 2=ws fused, 3=two-kernel.
    static int mode = -1;
    if (mode < 0) {
        int ncu = 0, dev = 0;
        (void)hipGetDevice(&dev);
        (void)hipDeviceGetAttribute(&ncu, hipDeviceAttributeMultiprocessorCount, dev);
        int nb = 0;
        hipFuncAttributes fa{};
        bool okReg = (hipOccupancyMaxActiveBlocksPerMultiprocessor(&nb, k_fused_reg, 256, 0) == hipSuccess)
                     && (nb * ncu >= NBLK)
                     && (hipFuncGetAttributes(&fa, (const void*)k_fused_reg) == hipSuccess)
                     && (fa.localSizeBytes == 0);
        nb = 0; fa = hipFuncAttributes{};
        bool okHalf = (hipOccupancyMaxActiveBlocksPerMultiprocessor(&nb, k_fused_half, 256, 0) == hipSuccess)
                      && (nb * ncu >= NBLK)
                      && (hipFuncGetAttributes(&fa, (const void*)k_fused_half) == hipSuccess)
                      && (fa.localSizeBytes == 0);
        nb = 0;
        bool okWs = (hipOccupancyMaxActiveBlocksPerMultiprocessor(&nb, k_fused_ws, 256, 0) == hipSuccess)
                    && (nb * ncu >= NBLK);
        if (okReg)                       mode = 0;
        else if (okHalf && store == 1)   mode = 1;
        else if (okWs && store == 1)     mode = 2;
        else                             mode = 3;
    }

    (void)hipMemsetAsync(ws, 0, 65536 + 64, stream);   // hist + rowdone

    if (mode == 0) {
        k_fused_reg<<<NBLK, 256, 0, stream>>>(x, hist, rowdone, out);
    } else if (mode == 1) {
        k_fused_half<<<NBLK, 256, 0, stream>>>(x, hist, rowdone, Abuf, Bbuf, l8buf, out);
    } else if (mode == 2) {
        k_fused_ws<<<NBLK, 256, 0, stream>>>(x, hist, rowdone, Abuf, Bbuf, l8buf, out);
    } else {
        k_hist_ab<<<NBLK, 256, 0, stream>>>(x, hist, Abuf, Bbuf, l8buf, store);
        k_lut_apply<<<NBLK, 256, 0, stream>>>(x, hist, Abuf, Bbuf, l8buf, out, store);
    }
}